// Round 4
// baseline (508.906 us; speedup 1.0000x reference)
//
#include <hip/hip_runtime.h>

#define NN 50000
#define EE 800000
#define DD 512
#define HH 8
#define NB 782            // bins of 64 nodes: 49999>>6 = 781 -> 782 bins
#define CAP 1280          // per-bin capacity (mean 1024, sd 32, +8 sigma; P(exceed)~5e-13)
#define GBLK 782          // gemm1 tile blocks (4 tiles each)
#define NTILE 3125        // NN/16 exact

typedef short bf16x8 __attribute__((ext_vector_type(8)));
typedef float f32x4 __attribute__((ext_vector_type(4)));

union U16 { uint4 u; bf16x8 v; unsigned short h[8]; };

__device__ __forceinline__ unsigned short f2bf(float f) {
    union { float f; unsigned int i; } c; c.f = f;
    unsigned int i = c.i;
    i += 0x7fffu + ((i >> 16) & 1u);   // RNE
    return (unsigned short)(i >> 16);
}

// ===== K1: gemm1 t1 = x @ W1 (bf16 MFMA, 16KB LDS, pipelined loads) ===========
__global__ __launch_bounds__(256) void k_gemm1(const float4* __restrict__ x4,
                                               const float* __restrict__ W1,
                                               float* __restrict__ t1) {
    __shared__ int smem[4096];                        // 16 KB
    int t = threadIdx.x;
    unsigned short* sbf = (unsigned short*)smem;      // [step][lane][j]
    for (int i = t; i < 16 * 64 * 8; i += 256) {
        int lane = (i >> 3) & 63, j = i & 7;
        int n = lane & 15;
        int k = (i >> 9) * 32 + ((lane >> 4) * 8) + j;
        sbf[i] = (n < HH) ? f2bf(W1[k * HH + n]) : (unsigned short)0;
    }
    __syncthreads();
    int wave = t >> 6, lane = t & 63;
    int tile = blockIdx.x * 4 + wave;
    if (tile >= NTILE) return;
    int node0 = tile * 16;
    int m = lane & 15, q = lane >> 4;
    const float4* xrow = x4 + (size_t)(node0 + m) * (DD / 4) + q * 2;
    const uint4* bfrag = (const uint4*)sbf;
    f32x4 acc = {0.f, 0.f, 0.f, 0.f};

    float4 bufA[8], bufB[8];
#define LOADG(buf, g)                                                      \
    _Pragma("unroll")                                                      \
    for (int s = 0; s < 4; ++s) {                                          \
        buf[2 * s]     = xrow[((g) * 4 + s) * 8];                          \
        buf[2 * s + 1] = xrow[((g) * 4 + s) * 8 + 1];                      \
    }
#define MFMAG(buf, g)                                                      \
    _Pragma("unroll")                                                      \
    for (int s = 0; s < 4; ++s) {                                          \
        U16 a, b;                                                          \
        float4 u0 = buf[2 * s], u1 = buf[2 * s + 1];                       \
        a.h[0] = f2bf(u0.x); a.h[1] = f2bf(u0.y);                          \
        a.h[2] = f2bf(u0.z); a.h[3] = f2bf(u0.w);                          \
        a.h[4] = f2bf(u1.x); a.h[5] = f2bf(u1.y);                          \
        a.h[6] = f2bf(u1.z); a.h[7] = f2bf(u1.w);                          \
        b.u = bfrag[((g) * 4 + s) * 64 + lane];                            \
        acc = __builtin_amdgcn_mfma_f32_16x16x32_bf16(a.v, b.v, acc, 0, 0, 0); \
    }
    LOADG(bufA, 0)
    LOADG(bufB, 1)
    MFMAG(bufA, 0)
    LOADG(bufA, 2)
    MFMAG(bufB, 1)
    LOADG(bufB, 3)
    MFMAG(bufA, 2)
    MFMAG(bufB, 3)
#undef LOADG
#undef MFMAG
    if (m < HH) {                                      // C: col=lane&15, row=q*4+r
        int base = (node0 + q * 4) * HH + m;
        t1[base]          = acc[0];
        t1[base + HH]     = acc[1];
        t1[base + 2 * HH] = acc[2];
        t1[base + 3 * HH] = acc[3];
    }
}

// ===== K2: direct-binning scatter via global atomic cursors ===================
// bin = dst>>6 (64 nodes/bin, fixed CAP slots). ~1k edges per cursor -> low
// same-address contention. Eliminates hist + both scans + blockhist entirely.
__global__ __launch_bounds__(256) void k_scatter(const int* __restrict__ eidx,
                                                 int* __restrict__ binCur,
                                                 int* __restrict__ bucket) {
    int t = threadIdx.x, b = blockIdx.x;
    int base = b * 1024;
#pragma unroll
    for (int it = 0; it < 4; ++it) {
        int i = base + it * 256 + t;
        if (i < EE) {
            int s = eidx[i], d = eidx[EE + i];
            int bin = d >> 6;
            int pos = atomicAdd(&binCur[bin], 1);
            if (pos < CAP) bucket[bin * CAP + pos] = (s << 6) | (d & 63);
        }
    }
}

// ===== K3: per-node degree -> dinvA; prescale t1 by dinv (fold sym-norm) ======
__global__ __launch_bounds__(256) void k_dinv(const int* __restrict__ bucket,
                                              const int* __restrict__ binCur,
                                              float* __restrict__ dinvA,
                                              float* __restrict__ t1) {
    __shared__ int cnt[64];
    __shared__ int cshare;
    int t = threadIdx.x, b = blockIdx.x;
    if (t < 64) cnt[t] = 0;
    if (t == 0) { int c = binCur[b]; cshare = (c > CAP) ? CAP : c; }
    __syncthreads();
    int count = cshare;
    const int* bk = bucket + b * CAP;
    for (int i = t; i < count; i += 256) atomicAdd(&cnt[bk[i] & 63], 1);
    __syncthreads();
    if (t < 64) {
        int n = (b << 6) + t;
        if (n < NN) {
            float dv = rsqrtf((float)cnt[t] + 1.0f);
            dinvA[n] = dv;
            float4* tp = (float4*)(t1 + (size_t)n * HH);  // t1' = t1 * dinv[n]
            float4 a = tp[0], c = tp[1];
            a.x *= dv; a.y *= dv; a.z *= dv; a.w *= dv;
            c.x *= dv; c.y *= dv; c.z *= dv; c.w *= dv;
            tp[0] = a; tp[1] = c;
        }
    }
}

// ===== K4: agg1 edge-parallel (LDS f32 atomics) + bias + LN + ReLU -> h2' =====
// No row/adj/sort: consume the unsorted bin bucket directly. Flat edge loop:
// zero wave divergence, perfect load balance. acc padded [64][9] vs bank hits.
__global__ __launch_bounds__(256) void k_agg1(const float* __restrict__ t1,
                                              const int* __restrict__ bucket,
                                              const int* __restrict__ binCur,
                                              const float* __restrict__ dinvA,
                                              const float* __restrict__ b1,
                                              const float* __restrict__ gma,
                                              const float* __restrict__ bta,
                                              float* __restrict__ h2) {
    __shared__ float acc[64 * 9];
    __shared__ int cshare;
    int t = threadIdx.x, b = blockIdx.x;
    int n0 = b << 6;
    for (int i = t; i < 512; i += 256) {               // init with self term (t1')
        int nl = i >> 3, f = i & 7;
        int n = n0 + nl;
        acc[nl * 9 + f] = (n < NN) ? t1[(size_t)n * HH + f] : 0.f;
    }
    if (t == 0) { int c = binCur[b]; cshare = (c > CAP) ? CAP : c; }
    __syncthreads();
    int count = cshare;
    const int* bk = bucket + b * CAP;
    for (int i = t; i < count; i += 256) {
        int p = bk[i];
        int s = p >> 6, dl = p & 63;
        const float4* sp = (const float4*)(t1 + (size_t)s * HH);
        float4 u0 = sp[0], u1 = sp[1];
        float* a = &acc[dl * 9];
        atomicAdd(a + 0, u0.x); atomicAdd(a + 1, u0.y);
        atomicAdd(a + 2, u0.z); atomicAdd(a + 3, u0.w);
        atomicAdd(a + 4, u1.x); atomicAdd(a + 5, u1.y);
        atomicAdd(a + 6, u1.z); atomicAdd(a + 7, u1.w);
    }
    __syncthreads();
    int nl2 = t >> 3, f = t & 7;                       // 32 nodes/pass, 8 thr/node
#pragma unroll
    for (int pass = 0; pass < 2; ++pass) {
        int nl = pass * 32 + nl2;
        int n = n0 + nl;
        if (n < NN) {
            float dv = dinvA[n];
            float v = acc[nl * 9 + f] * dv + b1[f];
            float s = v;
            s += __shfl_xor(s, 1); s += __shfl_xor(s, 2); s += __shfl_xor(s, 4);
            float mu = s * 0.125f;
            float dx = v - mu;
            float sq = dx * dx;
            sq += __shfl_xor(sq, 1); sq += __shfl_xor(sq, 2); sq += __shfl_xor(sq, 4);
            float rs = rsqrtf(sq * 0.125f + 1e-5f);
            h2[(size_t)n * HH + f] = fmaxf(dx * rs * gma[f] + bta[f], 0.f) * dv;
        }
    }
}

// ===== K5: agg2 edge-parallel + gemm2 (out = relu(agg @ W2 + b2) * sf) ========
__global__ __launch_bounds__(256) void k_agg2(const float* __restrict__ h2,
                                              const int* __restrict__ bucket,
                                              const int* __restrict__ binCur,
                                              const float* __restrict__ dinvA,
                                              const float* __restrict__ W2,
                                              const float* __restrict__ b2,
                                              const float* __restrict__ sf,
                                              float* __restrict__ out) {
    __shared__ float acc[64 * 9];
    __shared__ int cshare;
    int t = threadIdx.x, b = blockIdx.x;
    int n0 = b << 6;
    int c = t & 63, g = t >> 6, d0 = c * 8;
    float w[8][8];
#pragma unroll
    for (int k = 0; k < 8; ++k) {
        float4 u0 = *(const float4*)(W2 + k * DD + d0);
        float4 u1 = *(const float4*)(W2 + k * DD + d0 + 4);
        w[k][0] = u0.x; w[k][1] = u0.y; w[k][2] = u0.z; w[k][3] = u0.w;
        w[k][4] = u1.x; w[k][5] = u1.y; w[k][6] = u1.z; w[k][7] = u1.w;
    }
    float bb[8];
    {
        float4 u0 = *(const float4*)(b2 + d0);
        float4 u1 = *(const float4*)(b2 + d0 + 4);
        bb[0] = u0.x; bb[1] = u0.y; bb[2] = u0.z; bb[3] = u0.w;
        bb[4] = u1.x; bb[5] = u1.y; bb[6] = u1.z; bb[7] = u1.w;
    }
    for (int i = t; i < 512; i += 256) {               // init with self term (h2')
        int nl = i >> 3, f = i & 7;
        int n = n0 + nl;
        acc[nl * 9 + f] = (n < NN) ? h2[(size_t)n * HH + f] : 0.f;
    }
    if (t == 0) { int cc = binCur[b]; cshare = (cc > CAP) ? CAP : cc; }
    __syncthreads();
    int count = cshare;
    const int* bk = bucket + b * CAP;
    for (int i = t; i < count; i += 256) {
        int p = bk[i];
        int s = p >> 6, dl = p & 63;
        const float4* sp = (const float4*)(h2 + (size_t)s * HH);
        float4 u0 = sp[0], u1 = sp[1];
        float* a = &acc[dl * 9];
        atomicAdd(a + 0, u0.x); atomicAdd(a + 1, u0.y);
        atomicAdd(a + 2, u0.z); atomicAdd(a + 3, u0.w);
        atomicAdd(a + 4, u1.x); atomicAdd(a + 5, u1.y);
        atomicAdd(a + 6, u1.z); atomicAdd(a + 7, u1.w);
    }
    __syncthreads();
    for (int i = t; i < 512; i += 256) {               // finalize: * dinv[n]
        int nl = i >> 3, f = i & 7;
        int n = n0 + nl;
        if (n < NN) acc[nl * 9 + f] *= dinvA[n];
    }
    __syncthreads();
    // ---- gemm2: 64 nodes x 512 out; thread (g,c): nodes it*4+g, cols d0..d0+7
#pragma unroll
    for (int it = 0; it < 16; ++it) {
        int rrow = it * 4 + g;
        int n2 = n0 + rrow;
        if (n2 < NN) {
            float a[8];
#pragma unroll
            for (int j = 0; j < 8; ++j) a[j] = acc[rrow * 9 + j];
            float s = sf[n2];
            float o[8];
#pragma unroll
            for (int j = 0; j < 8; ++j) o[j] = bb[j];
#pragma unroll
            for (int k = 0; k < 8; ++k)
#pragma unroll
                for (int j = 0; j < 8; ++j) o[j] += a[k] * w[k][j];
            float4 o0 = make_float4(fmaxf(o[0], 0.f) * s, fmaxf(o[1], 0.f) * s,
                                    fmaxf(o[2], 0.f) * s, fmaxf(o[3], 0.f) * s);
            float4 o1 = make_float4(fmaxf(o[4], 0.f) * s, fmaxf(o[5], 0.f) * s,
                                    fmaxf(o[6], 0.f) * s, fmaxf(o[7], 0.f) * s);
            float4* op = (float4*)(out + (size_t)n2 * DD + d0);
            op[0] = o0;
            op[1] = o1;
        }
    }
}

extern "C" void kernel_launch(void* const* d_in, const int* in_sizes, int n_in,
                              void* d_out, int out_size, void* d_ws, size_t ws_size,
                              hipStream_t stream) {
    (void)in_sizes; (void)n_in; (void)out_size; (void)ws_size;
    const float* x   = (const float*)d_in[0];
    const float* sf  = (const float*)d_in[1];
    const float* W1  = (const float*)d_in[2];
    const float* b1  = (const float*)d_in[3];
    const float* gma = (const float*)d_in[4];
    const float* bta = (const float*)d_in[5];
    const float* W2  = (const float*)d_in[6];
    const float* b2  = (const float*)d_in[7];
    const int* eidx  = (const int*)d_in[8];
    float* out = (float*)d_out;

    char* ws = (char*)d_ws;
    int*   binCur = (int*)(ws + 0);                    // NB ints (3128 B)
    float* dinvA  = (float*)(ws + (1 << 20));          // NN f32
    float* t1     = (float*)(ws + 2 * (1 << 20));      // NN*8 f32 (1.6 MB)
    float* h2     = (float*)(ws + 4 * (1 << 20));      // NN*8 f32
    int*   bucket = (int*)(ws + 6 * (1 << 20));        // NB*CAP ints (4.0 MB)

    hipMemsetAsync(binCur, 0, NB * sizeof(int), stream);
    k_gemm1<<<GBLK, 256, 0, stream>>>((const float4*)x, W1, t1);
    k_scatter<<<NB, 256, 0, stream>>>(eidx, binCur, bucket);
    k_dinv<<<NB, 256, 0, stream>>>(bucket, binCur, dinvA, t1);
    k_agg1<<<NB, 256, 0, stream>>>(t1, bucket, binCur, dinvA, b1, gma, bta, h2);
    k_agg2<<<NB, 256, 0, stream>>>(h2, bucket, binCur, dinvA, W2, b2, sf, out);
}

// Round 5
// 316.579 us; speedup vs baseline: 1.6075x; 1.6075x over previous
//
#include <hip/hip_runtime.h>

#define NN 50000
#define EE 800000
#define DD 512
#define HH 8
#define GBLK 782          // gemm1 tile blocks (4 tiles each)
#define DBLK 391          // degree blocks fused into K1 (2048 edges each)
#define NTILE 3125        // NN/16 exact
#define AGBLK 1563        // ceil(NN*8/256)
#define SB 196            // scan blocks: 196*256 = 50176 >= NN
#define NPAD 50176        // padded node count for scans

typedef short bf16x8 __attribute__((ext_vector_type(8)));
typedef float f32x4 __attribute__((ext_vector_type(4)));

union U16 { uint4 u; bf16x8 v; unsigned short h[8]; };

__device__ __forceinline__ unsigned short f2bf(float f) {
    union { float f; unsigned int i; } c; c.f = f;
    unsigned int i = c.i;
    i += 0x7fffu + ((i >> 16) & 1u);   // RNE
    return (unsigned short)(i >> 16);
}

// ===== K1: gemm1 t1 = x @ W1 (blocks 0..GBLK-1) || degree count (atomics) =====
// deg atomics: 800k adds over 50k ints = 3125 cache lines (~256 adds/line,
// ~28cyc/line-RMW => ~3-6us), overlapped with the HBM-bound gemm. (r4 lesson:
// NEVER funnel 800k atomics into <100 lines.)
__global__ __launch_bounds__(256) void k_gemm1_deg(const float4* __restrict__ x4,
                                                   const float* __restrict__ W1,
                                                   const int* __restrict__ dst,
                                                   float* __restrict__ t1,
                                                   int* __restrict__ deg) {
    __shared__ int smem[4096];                        // 16 KB (gemm path only)
    int t = threadIdx.x;
    if (blockIdx.x >= GBLK) {
        // ---------------- degree path ----------------
        int base = (blockIdx.x - GBLK) * 2048;
#pragma unroll
        for (int it = 0; it < 8; ++it) {
            int i = base + it * 256 + t;
            if (i < EE) atomicAdd(&deg[dst[i]], 1);
        }
        return;
    }
    // ---------------- gemm1 path ----------------
    unsigned short* sbf = (unsigned short*)smem;      // [step][lane][j]
    for (int i = t; i < 16 * 64 * 8; i += 256) {
        int lane = (i >> 3) & 63, j = i & 7;
        int n = lane & 15;
        int k = (i >> 9) * 32 + ((lane >> 4) * 8) + j;
        sbf[i] = (n < HH) ? f2bf(W1[k * HH + n]) : (unsigned short)0;
    }
    __syncthreads();
    int wave = t >> 6, lane = t & 63;
    int tile = blockIdx.x * 4 + wave;
    if (tile >= NTILE) return;
    int node0 = tile * 16;
    int m = lane & 15, q = lane >> 4;
    const float4* xrow = x4 + (size_t)(node0 + m) * (DD / 4) + q * 2;
    const uint4* bfrag = (const uint4*)sbf;
    f32x4 acc = {0.f, 0.f, 0.f, 0.f};

    float4 bufA[8], bufB[8];
#define LOADG(buf, g)                                                      \
    _Pragma("unroll")                                                      \
    for (int s = 0; s < 4; ++s) {                                          \
        buf[2 * s]     = xrow[((g) * 4 + s) * 8];                          \
        buf[2 * s + 1] = xrow[((g) * 4 + s) * 8 + 1];                      \
    }
#define MFMAG(buf, g)                                                      \
    _Pragma("unroll")                                                      \
    for (int s = 0; s < 4; ++s) {                                          \
        U16 a, b;                                                          \
        float4 u0 = buf[2 * s], u1 = buf[2 * s + 1];                       \
        a.h[0] = f2bf(u0.x); a.h[1] = f2bf(u0.y);                          \
        a.h[2] = f2bf(u0.z); a.h[3] = f2bf(u0.w);                          \
        a.h[4] = f2bf(u1.x); a.h[5] = f2bf(u1.y);                          \
        a.h[6] = f2bf(u1.z); a.h[7] = f2bf(u1.w);                          \
        b.u = bfrag[((g) * 4 + s) * 64 + lane];                            \
        acc = __builtin_amdgcn_mfma_f32_16x16x32_bf16(a.v, b.v, acc, 0, 0, 0); \
    }
    LOADG(bufA, 0)
    LOADG(bufB, 1)
    MFMAG(bufA, 0)
    LOADG(bufA, 2)
    MFMAG(bufB, 1)
    LOADG(bufB, 3)
    MFMAG(bufA, 2)
    MFMAG(bufB, 3)
#undef LOADG
#undef MFMAG
    if (m < HH) {                                      // C: col=lane&15, row=q*4+r
        int base = (node0 + q * 4) * HH + m;
        t1[base]          = acc[0];
        t1[base + HH]     = acc[1];
        t1[base + 2 * HH] = acc[2];
        t1[base + 3 * HH] = acc[3];
    }
}

// ===== K2a: per-block local scan of deg -> dlocal (exclusive) + bsum ==========
__global__ __launch_bounds__(256) void k_scanA(const int* __restrict__ deg,
                                               int* __restrict__ dlocal,
                                               int* __restrict__ bsum) {
    __shared__ int s[256];
    int b = blockIdx.x, t = threadIdx.x;
    int n = b * 256 + t;
    int v = deg[n];                                   // padded region is 0
    s[t] = v; __syncthreads();
    for (int off = 1; off < 256; off <<= 1) {
        int x = (t >= off) ? s[t - off] : 0;
        __syncthreads();
        if (t >= off) s[t] += x;
        __syncthreads();
    }
    dlocal[n] = s[t] - v;
    if (t == 255) bsum[b] = s[255];
}

// ===== K2b: cross-block base + finalize row/cur/dinvA + prescale t1 ===========
__global__ __launch_bounds__(256) void k_scanB(const int* __restrict__ deg,
                                               const int* __restrict__ dlocal,
                                               const int* __restrict__ bsum,
                                               float* __restrict__ t1,
                                               int* __restrict__ row,
                                               int* __restrict__ cur,
                                               float* __restrict__ dinvA) {
    __shared__ int s[256];
    int b = blockIdx.x, t = threadIdx.x;
    s[t] = (t < SB) ? bsum[t] : 0;
    __syncthreads();
    for (int off = 1; off < 256; off <<= 1) {
        int x = (t >= off) ? s[t - off] : 0;
        __syncthreads();
        if (t >= off) s[t] += x;
        __syncthreads();
    }
    int base = s[b] - bsum[b];                        // exclusive across blocks
    int n = b * 256 + t;
    if (n < NN) {
        int r = base + dlocal[n];
        row[n] = r;
        cur[n] = r;
        float dv = rsqrtf((float)deg[n] + 1.0f);
        dinvA[n] = dv;
        float4* tp = (float4*)(t1 + (size_t)n * HH);  // t1' = t1 * dinv[n]
        float4 a = tp[0], c = tp[1];
        a.x *= dv; a.y *= dv; a.z *= dv; a.w *= dv;
        c.x *= dv; c.y *= dv; c.z *= dv; c.w *= dv;
        tp[0] = a; tp[1] = c;
    }
    if (b == 0 && t == 0) row[NN] = EE;
}

// ===== K3: CSR fill — adj[atomicAdd(cur[dst])] = src ==========================
__global__ __launch_bounds__(256) void k_fill(const int* __restrict__ eidx,
                                              int* __restrict__ cur,
                                              int* __restrict__ adj) {
    int i = blockIdx.x * 256 + threadIdx.x;           // 3125*256 = EE exactly
    int s = eidx[i], d = eidx[EE + i];
    int pos = atomicAdd(&cur[d], 1);
    adj[pos] = s;
}

// ===== K5: agg1 + bias + LayerNorm + ReLU -> h2' (pre-scaled by dinv) =========
__global__ __launch_bounds__(256) void k_agg1(const float* __restrict__ t1,
                                              const int* __restrict__ row,
                                              const int* __restrict__ adj,
                                              const float* __restrict__ dinvA,
                                              const float* __restrict__ b1,
                                              const float* __restrict__ gma,
                                              const float* __restrict__ bta,
                                              float* __restrict__ h2) {
    int gid = blockIdx.x * 256 + threadIdx.x;
    int n = gid >> 3, f = gid & 7;
    if (n >= NN) return;
    int beg = row[n], end = row[n + 1];
    float dv = dinvA[n];
    float acc = t1[(size_t)n * HH + f];               // self, already *dv
    int i = beg;
    for (; i < end && (i & 3); ++i)                   // align to 16B
        acc += t1[(size_t)adj[i] * HH + f];
    const int4* a4 = (const int4*)adj;
    for (; i + 8 <= end; i += 8) {
        int4 e0 = a4[i >> 2], e1 = a4[(i >> 2) + 1];
        float v0 = t1[(size_t)e0.x * HH + f], v1 = t1[(size_t)e0.y * HH + f];
        float v2 = t1[(size_t)e0.z * HH + f], v3 = t1[(size_t)e0.w * HH + f];
        float v4 = t1[(size_t)e1.x * HH + f], v5 = t1[(size_t)e1.y * HH + f];
        float v6 = t1[(size_t)e1.z * HH + f], v7 = t1[(size_t)e1.w * HH + f];
        acc += ((v0 + v1) + (v2 + v3)) + ((v4 + v5) + (v6 + v7));
    }
    if (i + 4 <= end) {
        int4 e0 = a4[i >> 2];
        float v0 = t1[(size_t)e0.x * HH + f], v1 = t1[(size_t)e0.y * HH + f];
        float v2 = t1[(size_t)e0.z * HH + f], v3 = t1[(size_t)e0.w * HH + f];
        acc += (v0 + v1) + (v2 + v3);
        i += 4;
    }
    for (; i < end; ++i)
        acc += t1[(size_t)adj[i] * HH + f];
    acc = acc * dv + b1[f];
    float s = acc;
    s += __shfl_xor(s, 1); s += __shfl_xor(s, 2); s += __shfl_xor(s, 4);
    float mu = s * 0.125f;
    float dx = acc - mu;
    float sq = dx * dx;
    sq += __shfl_xor(sq, 1); sq += __shfl_xor(sq, 2); sq += __shfl_xor(sq, 4);
    float rs = rsqrtf(sq * 0.125f + 1e-5f);
    h2[(size_t)n * HH + f] = fmaxf(dx * rs * gma[f] + bta[f], 0.f) * dv;  // h2'
}

// ===== K6: agg2 (phase A -> LDS, h2 pre-scaled) + gemm2 (phase B) =============
__global__ __launch_bounds__(256) void k_agg2_gemm2(const float* __restrict__ h2,
                                                    const int* __restrict__ row,
                                                    const int* __restrict__ adj,
                                                    const float* __restrict__ dinvA,
                                                    const float* __restrict__ W2,
                                                    const float* __restrict__ b2,
                                                    const float* __restrict__ sf,
                                                    float* __restrict__ out) {
    __shared__ float sA[32 * 8];
    int tid = threadIdx.x;
    int c = tid & 63, g = tid >> 6, d0 = c * 8;
    float w[8][8];
#pragma unroll
    for (int k = 0; k < 8; ++k) {
        float4 u0 = *(const float4*)(W2 + k * DD + d0);
        float4 u1 = *(const float4*)(W2 + k * DD + d0 + 4);
        w[k][0] = u0.x; w[k][1] = u0.y; w[k][2] = u0.z; w[k][3] = u0.w;
        w[k][4] = u1.x; w[k][5] = u1.y; w[k][6] = u1.z; w[k][7] = u1.w;
    }
    float bb[8];
    {
        float4 u0 = *(const float4*)(b2 + d0);
        float4 u1 = *(const float4*)(b2 + d0 + 4);
        bb[0] = u0.x; bb[1] = u0.y; bb[2] = u0.z; bb[3] = u0.w;
        bb[4] = u1.x; bb[5] = u1.y; bb[6] = u1.z; bb[7] = u1.w;
    }
    // ---- phase A: agg2 for 32 nodes (h2 is pre-scaled h2') ----
    int nl = tid >> 3, f = tid & 7;
    int n = blockIdx.x * 32 + nl;
    if (n < NN) {
        int beg = row[n], end = row[n + 1];
        float dv = dinvA[n];
        float acc = h2[(size_t)n * HH + f];           // self, already *dv
        int i = beg;
        for (; i < end && (i & 3); ++i)
            acc += h2[(size_t)adj[i] * HH + f];
        const int4* a4 = (const int4*)adj;
        for (; i + 8 <= end; i += 8) {
            int4 e0 = a4[i >> 2], e1 = a4[(i >> 2) + 1];
            float v0 = h2[(size_t)e0.x * HH + f], v1 = h2[(size_t)e0.y * HH + f];
            float v2 = h2[(size_t)e0.z * HH + f], v3 = h2[(size_t)e0.w * HH + f];
            float v4 = h2[(size_t)e1.x * HH + f], v5 = h2[(size_t)e1.y * HH + f];
            float v6 = h2[(size_t)e1.z * HH + f], v7 = h2[(size_t)e1.w * HH + f];
            acc += ((v0 + v1) + (v2 + v3)) + ((v4 + v5) + (v6 + v7));
        }
        if (i + 4 <= end) {
            int4 e0 = a4[i >> 2];
            float v0 = h2[(size_t)e0.x * HH + f], v1 = h2[(size_t)e0.y * HH + f];
            float v2 = h2[(size_t)e0.z * HH + f], v3 = h2[(size_t)e0.w * HH + f];
            acc += (v0 + v1) + (v2 + v3);
            i += 4;
        }
        for (; i < end; ++i)
            acc += h2[(size_t)adj[i] * HH + f];
        sA[nl * 8 + f] = acc * dv;
    }
    __syncthreads();
    // ---- phase B: out = relu(agg2 @ W2 + b2) * sf ----
#pragma unroll
    for (int i = 0; i < 8; ++i) {
        int rrow = i * 4 + g;
        int n2 = blockIdx.x * 32 + rrow;
        if (n2 < NN) {
            float a[8];
#pragma unroll
            for (int j = 0; j < 8; ++j) a[j] = sA[rrow * 8 + j];
            float s = sf[n2];
            float acc[8];
#pragma unroll
            for (int j = 0; j < 8; ++j) acc[j] = bb[j];
#pragma unroll
            for (int k = 0; k < 8; ++k)
#pragma unroll
                for (int j = 0; j < 8; ++j) acc[j] += a[k] * w[k][j];
            float4 o0 = make_float4(fmaxf(acc[0], 0.f) * s, fmaxf(acc[1], 0.f) * s,
                                    fmaxf(acc[2], 0.f) * s, fmaxf(acc[3], 0.f) * s);
            float4 o1 = make_float4(fmaxf(acc[4], 0.f) * s, fmaxf(acc[5], 0.f) * s,
                                    fmaxf(acc[6], 0.f) * s, fmaxf(acc[7], 0.f) * s);
            float4* op = (float4*)(out + (size_t)n2 * DD + d0);
            op[0] = o0;
            op[1] = o1;
        }
    }
}

extern "C" void kernel_launch(void* const* d_in, const int* in_sizes, int n_in,
                              void* d_out, int out_size, void* d_ws, size_t ws_size,
                              hipStream_t stream) {
    (void)in_sizes; (void)n_in; (void)out_size; (void)ws_size;
    const float* x   = (const float*)d_in[0];
    const float* sf  = (const float*)d_in[1];
    const float* W1  = (const float*)d_in[2];
    const float* b1  = (const float*)d_in[3];
    const float* gma = (const float*)d_in[4];
    const float* bta = (const float*)d_in[5];
    const float* W2  = (const float*)d_in[6];
    const float* b2  = (const float*)d_in[7];
    const int* eidx  = (const int*)d_in[8];
    float* out = (float*)d_out;

    char* ws = (char*)d_ws;
    int*   deg    = (int*)(ws + 0);                    // NPAD ints (196 KB)
    int*   dlocal = (int*)(ws + 0x40000);              // NPAD ints
    int*   bsum   = (int*)(ws + 0x80000);              // SB ints
    int*   row    = (int*)(ws + (1 << 20));            // NN+1 ints
    int*   cur    = (int*)(ws + 0x180000);             // NN ints
    float* dinvA  = (float*)(ws + 2 * (1 << 20));      // NN f32
    float* t1     = (float*)(ws + 3 * (1 << 20));      // NN*8 f32 (1.6 MB)
    float* h2     = (float*)(ws + 5 * (1 << 20));      // NN*8 f32
    int*   adj    = (int*)(ws + 7 * (1 << 20));        // EE ints (3.2 MB)

    hipMemsetAsync(deg, 0, NPAD * sizeof(int), stream);
    k_gemm1_deg<<<GBLK + DBLK, 256, 0, stream>>>((const float4*)x, W1, eidx + EE,
                                                 t1, deg);
    k_scanA<<<SB, 256, 0, stream>>>(deg, dlocal, bsum);
    k_scanB<<<SB, 256, 0, stream>>>(deg, dlocal, bsum, t1, row, cur, dinvA);
    k_fill<<<NTILE, 256, 0, stream>>>(eidx, cur, adj);
    k_agg1<<<AGBLK, 256, 0, stream>>>(t1, row, adj, dinvA, b1, gma, bta, h2);
    k_agg2_gemm2<<<AGBLK, 256, 0, stream>>>(h2, row, adj, dinvA, W2, b2, sf, out);
}